// Round 6
// baseline (88.838 us; speedup 1.0000x reference)
//
#include <hip/hip_runtime.h>
#include <math.h>

// LinearGating: B=4,S=4096,D=2048,E=64,K=2 -> N=16384 rows
// out (flat f32): [weights N*64][indices N*2 (as float)][logits N*64][probs N*64]
//
// fp16 split-3 MFMA GEMM: C[N x 128] = X[N x 2048] @ [Wg|Wn]
//   x = h + d, w = H + D;  acc1 += h*H ; acc2 += h*(D*2^6) + (d*2^6)*H
//   C = acc1 + acc2 * 2^-6
// R6: barrier-free k-loop. No LDS staging: each wave loads its own A/B
// fragments reg-direct from global (per-lane addresses), explicit 2-slice
// software pipeline. LDS only for the epilogue logits transpose.

typedef _Float16 f16;
typedef f16  f16x8  __attribute__((ext_vector_type(8)));
typedef float f32x16 __attribute__((ext_vector_type(16)));

constexpr int NROWS = 16384;
constexpr int DDIM  = 2048;
constexpr int NE    = 64;
constexpr int BM    = 32;
constexpr int NSL   = DDIM / 16;     // 128 k-slices of 16
constexpr float NSCALE = 1.0f / 4096.0f;

__device__ __forceinline__ float softplus_f(float x) {
    return fmaxf(x, 0.0f) + log1pf(expf(-fabsf(x)));
}

// ---------------- W prep: fragment-ordered fp16 {H, D*2^6} ----------------
// blob(S 0..127, f 0..3, v 0..1): lane l, elem j = Wcat[S*16+(l>>5)*8+j][f*32+(l&31)]
__global__ __launch_bounds__(256) void wprep_kernel(
    const float* __restrict__ Wg, const float* __restrict__ Wn,
    f16* __restrict__ ws)
{
    int t = blockIdx.x * 256 + threadIdx.x;    // 0..32767
    int S = t >> 8;
    int f = (t >> 6) & 3;
    int l = t & 63;
    int k0  = S * 16 + (l >> 5) * 8;
    int col = f * 32 + (l & 31);
    const float* src = (col < NE) ? (Wg + col) : (Wn + col - NE);
    f16x8 hp, lp;
    #pragma unroll
    for (int j = 0; j < 8; ++j) {
        float w  = src[(size_t)(k0 + j) * NE];
        f16 h    = (f16)w;
        float hf = (float)h;
        hp[j] = h;
        lp[j] = (f16)((w - hf) * 64.0f);
    }
    size_t base = (size_t)(S * 4 + f) * 1024;   // f16 units
    *(f16x8*)(ws + base + l * 8)       = hp;
    *(f16x8*)(ws + base + 512 + l * 8) = lp;
}

// ---------------- main fused kernel ----------------
__global__ __launch_bounds__(256, 2) void gemm_gating(
    const float* __restrict__ x, const f16* __restrict__ wfrag,
    const float* __restrict__ noise,
    float* __restrict__ out_w, float* __restrict__ out_idx,
    float* __restrict__ out_logits, float* __restrict__ out_probs)
{
    __shared__ float lgf[BM * 132];   // 16.9 KB, epilogue only
    const int tid = threadIdx.x;
    const int l   = tid & 63;
    const int w   = tid >> 6;      // wave 0..3; wave tile = 32 rows x cols [w*32, w*32+32)
    const int row0 = blockIdx.x * BM;

    f32x16 acc1, acc2;
    #pragma unroll
    for (int r = 0; r < 16; ++r) { acc1[r] = 0.0f; acc2[r] = 0.0f; }

    // per-lane fragment base addresses
    const float* aptr = x + (size_t)(row0 + (l & 31)) * DDIM + ((l >> 5) * 8);
    const f16*   bptr = wfrag + (size_t)w * 1024 + l * 8;   // + S*4096 per slice

    auto loadA = [&](int S, float4& a0, float4& a1) {
        const float* p = aptr + S * 16;
        a0 = *(const float4*)p;
        a1 = *(const float4*)(p + 4);
    };
    auto loadB = [&](int S, f16x8& bh, f16x8& bl) {
        const f16* p = bptr + (size_t)S * 4096;
        bh = *(const f16x8*)p;
        bl = *(const f16x8*)(p + 512);
    };
    auto compute = [&](const float4& a0, const float4& a1,
                       const f16x8& bh, const f16x8& bl) {
        float xs[8] = {a0.x, a0.y, a0.z, a0.w, a1.x, a1.y, a1.z, a1.w};
        f16x8 Ah, Al;
        #pragma unroll
        for (int j = 0; j < 8; ++j) {
            f16 h    = (f16)xs[j];
            float hf = (float)h;
            Ah[j] = h;
            Al[j] = (f16)((xs[j] - hf) * 64.0f);
        }
        acc1 = __builtin_amdgcn_mfma_f32_32x32x16_f16(Ah, bh, acc1, 0, 0, 0);
        acc2 = __builtin_amdgcn_mfma_f32_32x32x16_f16(Ah, bl, acc2, 0, 0, 0);
        acc2 = __builtin_amdgcn_mfma_f32_32x32x16_f16(Al, bh, acc2, 0, 0, 0);
    };

    // -------- barrier-free k-loop, 2-slice software pipeline --------
    float4 ra0, ra1, sa0, sa1;
    f16x8  rbh, rbl, sbh, sbl;
    loadA(0, ra0, ra1);
    loadB(0, rbh, rbl);

    #pragma unroll 2
    for (int t = 0; t < NSL / 2; ++t) {
        loadA(2 * t + 1, sa0, sa1);          // issue odd-slice loads
        loadB(2 * t + 1, sbh, sbl);
        compute(ra0, ra1, rbh, rbl);         // even slice
        if (t + 1 < NSL / 2) {
            loadA(2 * t + 2, ra0, ra1);      // issue next even-slice loads
            loadB(2 * t + 2, rbh, rbl);
        }
        compute(sa0, sa1, sbh, sbl);         // odd slice
    }

    // ---- scatter C to lgf[32][132] (cols 0..63 gate, 64..127 noise) ----
    #pragma unroll
    for (int r = 0; r < 16; ++r) {
        float cv = fmaf(acc2[r], 0.015625f, acc1[r]);
        int row = (r & 3) + 8 * (r >> 2) + 4 * (l >> 5);
        int col = w * 32 + (l & 31);
        lgf[row * 132 + col] = cv;
    }
    __syncthreads();

    // ---- phase1: noise injection -> noisy logits in lgf[:,0..63] + out_logits ----
    {
        const int pr = tid & 31;           // row
        const int c8 = tid >> 5;           // expert chunk of 8 (0..7)
        const int n1 = row0 + pr;
        const float4* gl4 = (const float4*)(lgf + pr * 132 + c8 * 8);
        const float4* nl4 = (const float4*)(lgf + pr * 132 + 64 + c8 * 8);
        const float4* nz4 = (const float4*)(noise + (size_t)n1 * NE + c8 * 8);
        float4* gw4 = (float4*)(lgf + pr * 132 + c8 * 8);
        float4* ol4 = (float4*)(out_logits + (size_t)n1 * NE + c8 * 8);
        #pragma unroll
        for (int q = 0; q < 2; ++q) {
            float4 G = gl4[q], NL = nl4[q], NZ = nz4[q];
            G.x += NZ.x * softplus_f(NL.x) * NSCALE;
            G.y += NZ.y * softplus_f(NL.y) * NSCALE;
            G.z += NZ.z * softplus_f(NL.z) * NSCALE;
            G.w += NZ.w * softplus_f(NL.w) * NSCALE;
            gw4[q] = G;
            ol4[q] = G;
        }
    }
    __syncthreads();

    // ---- phase2: per-row top-2 + softmax; 8 lanes/row x 32 rows ----
    {
        const int g2   = l >> 3;           // row within wave's 8-row group
        const int c    = l & 7;            // expert chunk of 8
        const int row2 = w * 8 + g2;
        const int n2   = row0 + row2;

        float mv[8];
        {
            const float4* mr = (const float4*)(lgf + row2 * 132 + c * 8);
            float4 m0 = mr[0], m1 = mr[1];
            mv[0]=m0.x; mv[1]=m0.y; mv[2]=m0.z; mv[3]=m0.w;
            mv[4]=m1.x; mv[5]=m1.y; mv[6]=m1.z; mv[7]=m1.w;
        }
        float v0 = -INFINITY, v1 = -INFINITY;
        int i0 = 0, i1 = 0;
        #pragma unroll
        for (int j = 0; j < 8; ++j) {
            float v = mv[j]; int e = c * 8 + j;
            if (v > v0) { v1 = v0; i1 = i0; v0 = v; i0 = e; }
            else if (v > v1) { v1 = v; i1 = e; }
        }
        #pragma unroll
        for (int m = 1; m <= 4; m <<= 1) {
            float ov0 = __shfl_xor(v0, m), ov1 = __shfl_xor(v1, m);
            int   oi0 = __shfl_xor(i0, m), oi1 = __shfl_xor(i1, m);
            if (ov0 > v0) {
                bool keep = (v0 > ov1);
                v1 = keep ? v0 : ov1; i1 = keep ? i0 : oi1;
                v0 = ov0; i0 = oi0;
            } else if (ov0 > v1) {
                v1 = ov0; i1 = oi0;
            }
        }
        const int srcl = l & 56;
        v0 = __shfl(v0, srcl); i0 = __shfl(i0, srcl);
        v1 = __shfl(v1, srcl); i1 = __shfl(i1, srcl);

        float se = 0.0f;
        #pragma unroll
        for (int j = 0; j < 8; ++j) se += expf(mv[j] - v0);
        se += __shfl_xor(se, 1); se += __shfl_xor(se, 2); se += __shfl_xor(se, 4);
        float inv_se = 1.0f / se;

        float t  = expf(v1 - v0);
        float w0 = 1.0f / (1.0f + t);
        float w1 = t * w0;

        float pr[8], wt[8];
        #pragma unroll
        for (int j = 0; j < 8; ++j) {
            int e = c * 8 + j;
            pr[j] = expf(mv[j] - v0) * inv_se;
            wt[j] = (e == i0) ? w0 : ((e == i1) ? w1 : 0.0f);
        }
        *(float4*)(out_probs + (size_t)n2 * NE + c * 8)     = make_float4(pr[0], pr[1], pr[2], pr[3]);
        *(float4*)(out_probs + (size_t)n2 * NE + c * 8 + 4) = make_float4(pr[4], pr[5], pr[6], pr[7]);
        *(float4*)(out_w + (size_t)n2 * NE + c * 8)         = make_float4(wt[0], wt[1], wt[2], wt[3]);
        *(float4*)(out_w + (size_t)n2 * NE + c * 8 + 4)     = make_float4(wt[4], wt[5], wt[6], wt[7]);
        if (c == 0) {
            *(float2*)(out_idx + (size_t)n2 * 2) = make_float2((float)i0, (float)i1);
        }
    }
}

extern "C" void kernel_launch(void* const* d_in, const int* in_sizes, int n_in,
                              void* d_out, int out_size, void* d_ws, size_t ws_size,
                              hipStream_t stream) {
    (void)in_sizes; (void)n_in; (void)ws_size; (void)out_size;
    const float* x     = (const float*)d_in[0];
    const float* Wg    = (const float*)d_in[1];
    const float* Wn    = (const float*)d_in[2];
    const float* noise = (const float*)d_in[3];
    float* out        = (float*)d_out;
    float* out_w      = out;
    float* out_idx    = out + (size_t)NROWS * NE;
    float* out_logits = out_idx + (size_t)NROWS * 2;
    float* out_probs  = out_logits + (size_t)NROWS * NE;
    f16* wfrag = (f16*)d_ws;   // 1 MB

    wprep_kernel<<<128, 256, 0, stream>>>(Wg, Wn, wfrag);
    gemm_gating<<<NROWS / BM, 256, 0, stream>>>(
        x, wfrag, noise, out_w, out_idx, out_logits, out_probs);
}

// Round 7
// 57.937 us; speedup vs baseline: 1.5334x; 1.5334x over previous
//
#include <hip/hip_runtime.h>
#include <math.h>

// LinearGating: B=4,S=4096,D=2048,E=64,K=2 -> N=16384 rows
// out (flat f32): [weights N*64][indices N*2 (as float)][logits N*64][probs N*64]
//
// fp16 split-3 MFMA GEMM: C[N x 128] = X[N x 2048] @ [Wg|Wn]
//   x = h + d, w = H + D;  acc1 += h*H ; acc2 += h*(D*2^6) + (d*2^6)*H
//   C = acc1 + acc2 * 2^-6
// R7: R5 structure + counted-vmcnt pipeline (T3/T4): 3 LDS buffers, 2-deep
// prefetch, raw s_barrier with s_waitcnt vmcnt(6/4) instead of the
// __syncthreads vmcnt(0) drain. Tail iters drain fully.

typedef _Float16 f16;
typedef f16  f16x8  __attribute__((ext_vector_type(8)));
typedef float f32x16 __attribute__((ext_vector_type(16)));

constexpr int NROWS = 16384;
constexpr int DDIM  = 2048;
constexpr int NE    = 64;
constexpr int BM    = 32;
constexpr int KI    = 32;            // k per iteration (2 MFMA k-slices)
constexpr int NITER = DDIM / KI;     // 64
constexpr float NSCALE = 1.0f / 4096.0f;

__device__ __forceinline__ float softplus_f(float x) {
    return fmaxf(x, 0.0f) + log1pf(expf(-fabsf(x)));
}

// LDS layout (3 buffers):
// A: [0, 12K)   buf*4K + (v*2+s)*1K      (1KB blob = 64 lanes x 16B)
// B: [12K, 60K) 12K + buf*16K + ((v*4+f)*2+s)*1K
__device__ __forceinline__ int a_off(int buf, int v, int s) {
    return buf * 4096 + (v * 2 + s) * 1024;
}
__device__ __forceinline__ int b_off(int buf, int v, int f, int s) {
    return 12288 + buf * 16384 + (((v * 4) + f) * 2 + s) * 1024;
}

__device__ __forceinline__ void gload_lds16(const void* g, void* l) {
    __builtin_amdgcn_global_load_lds(
        (const __attribute__((address_space(1))) void*)g,
        (__attribute__((address_space(3))) void*)l, 16, 0, 0);
}

// barrier A: close compute window (LDS reads drained; no vm wait)
__device__ __forceinline__ void barrier_close() {
    asm volatile("s_waitcnt lgkmcnt(0)" ::: "memory");
    __builtin_amdgcn_sched_barrier(0);
    __builtin_amdgcn_s_barrier();
    asm volatile("" ::: "memory");
}
// barrier B: publish buf(t+1); keep this iter's 6 (or 4) loads in flight
__device__ __forceinline__ void barrier_publish_steady(bool heavy) {
    if (heavy) asm volatile("s_waitcnt vmcnt(6) lgkmcnt(0)" ::: "memory");
    else       asm volatile("s_waitcnt vmcnt(4) lgkmcnt(0)" ::: "memory");
    __builtin_amdgcn_sched_barrier(0);
    __builtin_amdgcn_s_barrier();
    asm volatile("" ::: "memory");
    __builtin_amdgcn_sched_barrier(0);
}
__device__ __forceinline__ void barrier_publish_drain() {
    asm volatile("s_waitcnt vmcnt(0) lgkmcnt(0)" ::: "memory");
    __builtin_amdgcn_sched_barrier(0);
    __builtin_amdgcn_s_barrier();
    asm volatile("" ::: "memory");
    __builtin_amdgcn_sched_barrier(0);
}

// ---------------- W prep: fragment-ordered fp16 {H, D*2^6} ----------------
// blob(S 0..127, f 0..3, v 0..1): lane l, elem j = Wcat[S*16+(l>>5)*8+j][f*32+(l&31)]
__global__ __launch_bounds__(256) void wprep_kernel(
    const float* __restrict__ Wg, const float* __restrict__ Wn,
    f16* __restrict__ ws)
{
    int t = blockIdx.x * 256 + threadIdx.x;    // 0..32767
    int S = t >> 8;
    int f = (t >> 6) & 3;
    int l = t & 63;
    int k0  = S * 16 + (l >> 5) * 8;
    int col = f * 32 + (l & 31);
    const float* src = (col < NE) ? (Wg + col) : (Wn + col - NE);
    f16x8 hp, lp;
    #pragma unroll
    for (int j = 0; j < 8; ++j) {
        float w  = src[(size_t)(k0 + j) * NE];
        f16 h    = (f16)w;
        float hf = (float)h;
        hp[j] = h;
        lp[j] = (f16)((w - hf) * 64.0f);
    }
    size_t base = (size_t)(S * 4 + f) * 1024;   // f16 units
    *(f16x8*)(ws + base + l * 8)       = hp;
    *(f16x8*)(ws + base + 512 + l * 8) = lp;
}

// ---------------- main fused kernel ----------------
__global__ __launch_bounds__(256, 2) void gemm_gating(
    const float* __restrict__ x, const f16* __restrict__ wfrag,
    const float* __restrict__ noise,
    float* __restrict__ out_w, float* __restrict__ out_idx,
    float* __restrict__ out_logits, float* __restrict__ out_probs)
{
    __shared__ __align__(16) char smem[61440];   // 60 KB: A 12K + B 48K
    const int tid = threadIdx.x;
    const int l   = tid & 63;
    const int w   = tid >> 6;      // wave 0..3; wave tile = 32 rows x cols [w*32, w*32+32)
    const bool heavy = (w < 2);    // waves 0,1 also stage A
    const int row0 = blockIdx.x * BM;

    f32x16 acc1, acc2;
    #pragma unroll
    for (int r = 0; r < 16; ++r) { acc1[r] = 0.0f; acc2[r] = 0.0f; }

    // --- A staging (waves 0,1): wave w owns k-slice s=w of each iter ---
    // lane l: row = l&31, k = i*32 + w*16 + (l>>5)*8
    const float* xrow = x + (size_t)(row0 + (l & 31)) * DDIM + w * 16 + (l >> 5) * 8;

    auto loadA = [&](int i, float4& a0, float4& a1) {
        if (heavy) {
            const float* p = xrow + i * KI;
            a0 = *(const float4*)p;
            a1 = *(const float4*)(p + 4);
        }
    };
    auto writeA = [&](const float4& a0, const float4& a1, int buf) {
        if (heavy) {
            float xs[8] = {a0.x, a0.y, a0.z, a0.w, a1.x, a1.y, a1.z, a1.w};
            f16x8 hp, lp;
            #pragma unroll
            for (int j = 0; j < 8; ++j) {
                f16 h    = (f16)xs[j];
                float hf = (float)h;
                hp[j] = h;
                lp[j] = (f16)((xs[j] - hf) * 64.0f);
            }
            *(f16x8*)(smem + a_off(buf, 0, w) + l * 16) = hp;
            *(f16x8*)(smem + a_off(buf, 1, w) + l * 16) = lp;
        }
    };
    // --- B staging: wave w stages its own col-quad f=w (4 gload_lds/iter) ---
    auto stageB = [&](int i, int buf) {
        #pragma unroll
        for (int v = 0; v < 2; ++v)
            #pragma unroll
            for (int s = 0; s < 2; ++s) {
                int S = i * 2 + s;
                const f16* src = wfrag + (size_t)(S * 4 + w) * 1024 + v * 512 + l * 8;
                gload_lds16(src, smem + b_off(buf, v, w, s));
            }
    };
    auto compute = [&](int buf) {
        #pragma unroll
        for (int s = 0; s < 2; ++s) {
            f16x8 Ah = *(const f16x8*)(smem + a_off(buf, 0, s) + l * 16);
            f16x8 Al = *(const f16x8*)(smem + a_off(buf, 1, s) + l * 16);
            f16x8 Bh = *(const f16x8*)(smem + b_off(buf, 0, w, s) + l * 16);
            f16x8 Bl = *(const f16x8*)(smem + b_off(buf, 1, w, s) + l * 16);
            acc1 = __builtin_amdgcn_mfma_f32_32x32x16_f16(Ah, Bh, acc1, 0, 0, 0);
            acc2 = __builtin_amdgcn_mfma_f32_32x32x16_f16(Ah, Bl, acc2, 0, 0, 0);
            acc2 = __builtin_amdgcn_mfma_f32_32x32x16_f16(Al, Bh, acc2, 0, 0, 0);
        }
    };

    // -------- prologue: issue iters 0,1; publish buf0 --------
    float4 t0a, t0b, nxt0, nxt1;
    loadA(0, t0a, t0b);
    stageB(0, 0);
    loadA(1, nxt0, nxt1);
    stageB(1, 1);
    writeA(t0a, t0b, 0);      // compiler waits A(0) regs only

    int b0 = 0, b1 = 1, b2 = 2;
    for (int t = 0; t < NITER; ++t) {
        barrier_close();                       // peers done computing t-1
        float4 ld0 = nxt0, ld1 = nxt1;
        if (t + 2 < NITER) {
            stageB(t + 2, b2);                 // DMA into buf freed by compute(t-1)
            loadA(t + 2, ld0, ld1);
        }
        if (t + 1 < NITER) writeA(nxt0, nxt1, b1);
        nxt0 = ld0; nxt1 = ld1;
        if (t + 2 < NITER) barrier_publish_steady(heavy);
        else               barrier_publish_drain();
        compute(b0);
        int tmp = b0; b0 = b1; b1 = b2; b2 = tmp;
    }
    __syncthreads();   // full drain before smem reuse

    // ---- scatter C to lgf[32][132] (cols 0..63 gate, 64..127 noise) ----
    float* lgf = (float*)smem;
    #pragma unroll
    for (int r = 0; r < 16; ++r) {
        float cv = fmaf(acc2[r], 0.015625f, acc1[r]);
        int row = (r & 3) + 8 * (r >> 2) + 4 * (l >> 5);
        int col = w * 32 + (l & 31);
        lgf[row * 132 + col] = cv;
    }
    __syncthreads();

    // ---- phase1: noise injection -> noisy logits in lgf[:,0..63] + out_logits ----
    {
        const int pr = tid & 31;           // row
        const int c8 = tid >> 5;           // expert chunk of 8 (0..7)
        const int n1 = row0 + pr;
        const float4* gl4 = (const float4*)(lgf + pr * 132 + c8 * 8);
        const float4* nl4 = (const float4*)(lgf + pr * 132 + 64 + c8 * 8);
        const float4* nz4 = (const float4*)(noise + (size_t)n1 * NE + c8 * 8);
        float4* gw4 = (float4*)(lgf + pr * 132 + c8 * 8);
        float4* ol4 = (float4*)(out_logits + (size_t)n1 * NE + c8 * 8);
        #pragma unroll
        for (int q = 0; q < 2; ++q) {
            float4 G = gl4[q], NL = nl4[q], NZ = nz4[q];
            G.x += NZ.x * softplus_f(NL.x) * NSCALE;
            G.y += NZ.y * softplus_f(NL.y) * NSCALE;
            G.z += NZ.z * softplus_f(NL.z) * NSCALE;
            G.w += NZ.w * softplus_f(NL.w) * NSCALE;
            gw4[q] = G;
            ol4[q] = G;
        }
    }
    __syncthreads();

    // ---- phase2: per-row top-2 + softmax; 8 lanes/row x 32 rows ----
    {
        const int g2   = l >> 3;           // row within wave's 8-row group
        const int c    = l & 7;            // expert chunk of 8
        const int row2 = w * 8 + g2;
        const int n2   = row0 + row2;

        float mv[8];
        {
            const float4* mr = (const float4*)(lgf + row2 * 132 + c * 8);
            float4 m0 = mr[0], m1 = mr[1];
            mv[0]=m0.x; mv[1]=m0.y; mv[2]=m0.z; mv[3]=m0.w;
            mv[4]=m1.x; mv[5]=m1.y; mv[6]=m1.z; mv[7]=m1.w;
        }
        float v0 = -INFINITY, v1 = -INFINITY;
        int i0 = 0, i1 = 0;
        #pragma unroll
        for (int j = 0; j < 8; ++j) {
            float v = mv[j]; int e = c * 8 + j;
            if (v > v0) { v1 = v0; i1 = i0; v0 = v; i0 = e; }
            else if (v > v1) { v1 = v; i1 = e; }
        }
        #pragma unroll
        for (int m = 1; m <= 4; m <<= 1) {
            float ov0 = __shfl_xor(v0, m), ov1 = __shfl_xor(v1, m);
            int   oi0 = __shfl_xor(i0, m), oi1 = __shfl_xor(i1, m);
            if (ov0 > v0) {
                bool keep = (v0 > ov1);
                v1 = keep ? v0 : ov1; i1 = keep ? i0 : oi1;
                v0 = ov0; i0 = oi0;
            } else if (ov0 > v1) {
                v1 = ov0; i1 = oi0;
            }
        }
        const int srcl = l & 56;
        v0 = __shfl(v0, srcl); i0 = __shfl(i0, srcl);
        v1 = __shfl(v1, srcl); i1 = __shfl(i1, srcl);

        float se = 0.0f;
        #pragma unroll
        for (int j = 0; j < 8; ++j) se += expf(mv[j] - v0);
        se += __shfl_xor(se, 1); se += __shfl_xor(se, 2); se += __shfl_xor(se, 4);
        float inv_se = 1.0f / se;

        float t  = expf(v1 - v0);
        float w0 = 1.0f / (1.0f + t);
        float w1 = t * w0;

        float pr[8], wt[8];
        #pragma unroll
        for (int j = 0; j < 8; ++j) {
            int e = c * 8 + j;
            pr[j] = expf(mv[j] - v0) * inv_se;
            wt[j] = (e == i0) ? w0 : ((e == i1) ? w1 : 0.0f);
        }
        *(float4*)(out_probs + (size_t)n2 * NE + c * 8)     = make_float4(pr[0], pr[1], pr[2], pr[3]);
        *(float4*)(out_probs + (size_t)n2 * NE + c * 8 + 4) = make_float4(pr[4], pr[5], pr[6], pr[7]);
        *(float4*)(out_w + (size_t)n2 * NE + c * 8)         = make_float4(wt[0], wt[1], wt[2], wt[3]);
        *(float4*)(out_w + (size_t)n2 * NE + c * 8 + 4)     = make_float4(wt[4], wt[5], wt[6], wt[7]);
        if (c == 0) {
            *(float2*)(out_idx + (size_t)n2 * 2) = make_float2((float)i0, (float)i1);
        }
    }
}

extern "C" void kernel_launch(void* const* d_in, const int* in_sizes, int n_in,
                              void* d_out, int out_size, void* d_ws, size_t ws_size,
                              hipStream_t stream) {
    (void)in_sizes; (void)n_in; (void)ws_size; (void)out_size;
    const float* x     = (const float*)d_in[0];
    const float* Wg    = (const float*)d_in[1];
    const float* Wn    = (const float*)d_in[2];
    const float* noise = (const float*)d_in[3];
    float* out        = (float*)d_out;
    float* out_w      = out;
    float* out_idx    = out + (size_t)NROWS * NE;
    float* out_logits = out_idx + (size_t)NROWS * 2;
    float* out_probs  = out_logits + (size_t)NROWS * NE;
    f16* wfrag = (f16*)d_ws;   // 1 MB

    wprep_kernel<<<128, 256, 0, stream>>>(Wg, Wn, wfrag);
    gemm_gating<<<NROWS / BM, 256, 0, stream>>>(
        x, wfrag, noise, out_w, out_idx, out_logits, out_probs);
}